// Round 17
// baseline (130.218 us; speedup 1.0000x reference)
//
#include <hip/hip_runtime.h>
#include <hip/hip_bf16.h>
#include <stdint.h>

#define N_B 2
#define T_S 2048
#define D_M 1024
#define H_N 16
#define D_H 64

typedef __bf16 bf16_t;
typedef __bf16 bf16x8 __attribute__((ext_vector_type(8)));
typedef float f32x4 __attribute__((ext_vector_type(4)));
typedef float f32x16 __attribute__((ext_vector_type(16)));

__device__ __forceinline__ void async_ld16(const void* g, void* lds_uniform_base) {
  __builtin_amdgcn_global_load_lds(
      (const __attribute__((address_space(1))) uint32_t*)(uintptr_t)g,
      (__attribute__((address_space(3))) uint32_t*)(uintptr_t)lds_uniform_base,
      16, 0, 0);
}

// ---------------- prep: fp32->bf16 cvt (x, proj_w) + W transpose-cvt -------
__global__ __launch_bounds__(256) void prep_kernel(
    const float* __restrict__ x, bf16_t* __restrict__ x_bf,
    const float* __restrict__ pw, bf16_t* __restrict__ pwb,
    const float* __restrict__ W, bf16_t* __restrict__ Wt) {
  __shared__ float tile[32][33];
  const int bid = blockIdx.x;
  if (bid < 5120) {
    int i = bid * 256 + threadIdx.x;
    const float* in = x;
    bf16_t* out = x_bf;
    const int n1 = (4096 * 1024) / 4;
    if (i >= n1) { i -= n1; in = pw; out = pwb; }
    float4 v = ((const float4*)in)[i];
    union { bf16_t b[4]; uint64_t u; } o;
    o.b[0] = (bf16_t)v.x; o.b[1] = (bf16_t)v.y;
    o.b[2] = (bf16_t)v.z; o.b[3] = (bf16_t)v.w;
    *(uint64_t*)(out + (size_t)i * 4) = o.u;
  } else {
    const int tb = bid - 5120;            // 0..3071
    const int bx = (tb % 96) * 32;        // col of W
    const int by = (tb / 96) * 32;        // row of W
    const int tx = threadIdx.x & 31, ty = threadIdx.x >> 5;  // (32,8)
#pragma unroll
    for (int i = 0; i < 32; i += 8)
      tile[ty + i][tx] = W[(size_t)(by + ty + i) * 3072 + bx + tx];
    __syncthreads();
#pragma unroll
    for (int i = 0; i < 32; i += 8)
      Wt[(size_t)(bx + ty + i) * 1024 + by + tx] = (bf16_t)tile[tx][ty + i];
  }
}

// ---------------- bf16 GEMM, C = A @ Bt^T : 128 x BN tile, BK=32 -----------
// r12 pipeline (best measured: 44.0us at BN=128): 2-buffer, counted vmcnt,
// two barriers/step, linear LDS (conflicts measured off-critical-path).
// NARROWER TILES for occupancy: BN=96 -> QKV grid 1024 = 4 blocks/CU
// (16 waves/CU, was 3 blocks/12 waves); BN=64 -> proj grid 512 = 2 blocks/CU.
// LDS: 2 x (8KB A + BN*64B B). Per-wave DMA in-flight count nld differs
// (chunks not a multiple of 256) -> wave-uniform vmcnt(4)/vmcnt(3) branch.
// MODE 0: scatter into Q/K/Vt head layouts.  MODE 1: +bias, fp32 out.
template <int MODE, int BN>
__global__ __launch_bounds__(256) void gemm_bt_kernel(
    const bf16_t* __restrict__ A, const bf16_t* __restrict__ Bt,
    bf16_t* __restrict__ Qo, bf16_t* __restrict__ Ko, bf16_t* __restrict__ Vto,
    const float* __restrict__ bias, float* __restrict__ Co,
    int nbx, int cpx) {
  constexpr int NF = BN / 32;              // B frags per wave (cols = BN/2)
  constexpr int CH = (128 + BN) * 4;       // 16B chunks per K-tile
  constexpr int BUFB = 8192 + BN * 64;     // bytes per buffer
  __shared__ char lds[2][BUFB];

  const int tid = threadIdx.x;
  const int lane = tid & 63;
  const int wid = tid >> 6;
  const int wr = wid >> 1, wc = wid & 1;
  const int g = lane >> 4, lr = lane & 15;
  const int d_ = blockIdx.x;
  const int orig = (d_ & 7) * cpx + (d_ >> 3);
  const int brow = (orig / nbx) * 128;
  const int bcol = (orig % nbx) * BN;

  f32x4 acc[4][NF] = {};

  // staging: chunk c -> A (c<512): row c>>2, 16B-slot c&3;  B: cb=c-512.
  const char* gbase[4];
  int sdst[4], nq = 0;
#pragma unroll
  for (int q = 0; q < 4; ++q) {
    int c = q * 256 + tid;
    if (c < CH) {
      if (c < 512) {
        gbase[nq] = (const char*)A + (size_t)(brow + (c >> 2)) * 2048 + (c & 3) * 16;
        sdst[nq] = c * 16;
      } else {
        int cb = c - 512;
        gbase[nq] = (const char*)Bt + (size_t)(bcol + (cb >> 2)) * 2048 + (cb & 3) * 16;
        sdst[nq] = 8192 + cb * 16;
      }
      ++nq;
    }
  }
  const int nld = nq;  // wave-uniform (CH multiple of 64)

  auto stage = [&](int t, int b) {
#pragma unroll
    for (int q = 0; q < 4; ++q)
      if (q < nld) async_ld16(gbase[q] + t * 64, lds[b] + sdst[q]);
  };

  stage(0, 0);
  for (int t = 0; t < 32; ++t) {
    if (t + 1 < 32) {
      stage(t + 1, (t + 1) & 1);
      if (nld == 4) { asm volatile("s_waitcnt vmcnt(4)" ::: "memory"); }
      else          { asm volatile("s_waitcnt vmcnt(3)" ::: "memory"); }
    } else {
      asm volatile("s_waitcnt vmcnt(0)" ::: "memory");
    }
    __builtin_amdgcn_s_barrier();
    __builtin_amdgcn_sched_barrier(0);

    const char* base = lds[t & 1];
    bf16x8 af[4], bfr[NF];
#pragma unroll
    for (int i = 0; i < 4; ++i)
      af[i] = *(const bf16x8*)(base + (wr * 64 + i * 16 + lr) * 64 + g * 16);
#pragma unroll
    for (int j = 0; j < NF; ++j)
      bfr[j] = *(const bf16x8*)(base + 8192 + (wc * (BN / 2) + j * 16 + lr) * 64 + g * 16);
    __builtin_amdgcn_s_setprio(1);
#pragma unroll
    for (int i = 0; i < 4; ++i)
#pragma unroll
      for (int j = 0; j < NF; ++j)
        acc[i][j] = __builtin_amdgcn_mfma_f32_16x16x32_bf16(af[i], bfr[j], acc[i][j], 0, 0, 0);
    __builtin_amdgcn_s_setprio(0);
    asm volatile("s_waitcnt lgkmcnt(0)" ::: "memory");  // reads retired before overwrite
    __builtin_amdgcn_s_barrier();
  }

#pragma unroll
  for (int i = 0; i < 4; ++i) {
    int row0_ = brow + wr * 64 + i * 16 + g * 4;
#pragma unroll
    for (int j = 0; j < NF; ++j) {
      int col = bcol + wc * (BN / 2) + j * 16 + lr;
#pragma unroll
      for (int r = 0; r < 4; ++r) {
        int row = row0_ + r;
        float v = acc[i][j][r];
        if (MODE == 0) {
          int n = row >> 11, t = row & (T_S - 1);
          int which = col >> 10, d = col & (D_M - 1);
          int h = d >> 6, dh = d & 63;
          if (which == 0)
            Qo[((size_t)(n * H_N + h) * T_S + t) * D_H + dh] = (bf16_t)v;
          else if (which == 1)
            Ko[((size_t)(n * H_N + h) * T_S + t) * D_H + dh] = (bf16_t)v;
          else
            Vto[((size_t)(n * H_N + h) * D_H + dh) * T_S + t] = (bf16_t)v;
        } else {
          Co[(size_t)row * D_M + col] = v + bias[col];
        }
      }
    }
  }
}

// ---------------- causal flash attention (swapped-QK, 32x32 MFMA) ----------
// (r9 structure, unchanged)
__global__ __launch_bounds__(256, 4) void attn_kernel(const bf16_t* __restrict__ Q,
                                                      const bf16_t* __restrict__ K,
                                                      const bf16_t* __restrict__ Vt,
                                                      bf16_t* __restrict__ O) {
  __shared__ bf16_t Ks[2][4096];
  __shared__ bf16_t Vs[2][4096];
  __shared__ float Linv[64];

  const int tid = threadIdx.x;
  const int lane = tid & 63;
  const int w = tid >> 6;
  const int qsub = w >> 1, khalf = w & 1;
  const int l31 = lane & 31;
  const int hi = lane >> 5;

  const int d_ = blockIdx.x;       // 0..1023
  const int x = d_ & 7;
  const int s = d_ >> 3;
  const int hs = s & 3, j_ = s >> 2;
  const int t_ = j_ >> 3, m_ = j_ & 7;
  const int qc = (t_ == 0) ? (31 - m_) : (t_ == 1) ? (16 + m_)
               : (t_ == 2) ? (15 - m_) : m_;
  const int nh = x * 4 + hs;
  const bf16_t* Qg = Q + (size_t)nh * T_S * D_H;
  const char* Kb = (const char*)(K + (size_t)nh * T_S * D_H);
  const char* Vb = (const char*)(Vt + (size_t)nh * D_H * T_S);
  const int n = nh >> 4, h = nh & 15;

  const int c0 = (w * 2 + 0) * 64 + lane;
  const int c1 = (w * 2 + 1) * 64 + lane;
  const int r0_ = c0 >> 3, cb0 = (c0 & 7) * 16, sw0 = (r0_ & 7) << 4;
  const int r1_ = c1 >> 3, cb1 = (c1 & 7) * 16, sw1 = (r1_ & 7) << 4;
  const int koff0 = r0_ * 128 + (cb0 ^ sw0), koff1 = r1_ * 128 + (cb1 ^ sw1);
  const int voff0 = r0_ * 4096 + (cb0 ^ sw0), voff1 = r1_ * 4096 + (cb1 ^ sw1);
  const int lds0 = (w * 2 + 0) * 1024, lds1 = (w * 2 + 1) * 1024;

  const int q0w = qc * 64 + qsub * 32;
  const int nt = qc + 1;

  bf16x8 qf[4];
#pragma unroll
  for (int ksd = 0; ksd < 4; ++ksd) {
    bf16x8 t = *(const bf16x8*)(Qg + (size_t)(q0w + l31) * D_H + ksd * 16 + hi * 8);
#pragma unroll
    for (int e = 0; e < 8; ++e) t[e] = (bf16_t)((float)t[e] * 0.125f);
    qf[ksd] = t;
  }

  const int kabs_ = khalf * 32 + l31;
  int kfo[4];
#pragma unroll
  for (int ksd = 0; ksd < 4; ++ksd)
    kfo[ksd] = (kabs_ * 128 + ksd * 32 + hi * 16) ^ ((kabs_ & 7) << 4);
  int vfo[2][2];
#pragma unroll
  for (int db = 0; db < 2; ++db)
#pragma unroll
    for (int kk = 0; kk < 2; ++kk) {
      int dd = db * 32 + l31;
      vfo[db][kk] = (dd * 128 + khalf * 64 + kk * 32 + hi * 16) ^ ((dd & 7) << 4);
    }

  f32x16 oacc[2] = {};
  float lsum = 0.f;

  auto issue = [&](int t, int b) {
    const char* kt_ = Kb + (size_t)t * 8192;
    const char* vt_ = Vb + (size_t)t * 128;
    async_ld16(kt_ + koff0, (char*)Ks[b] + lds0);
    async_ld16(kt_ + koff1, (char*)Ks[b] + lds1);
    async_ld16(vt_ + voff0, (char*)Vs[b] + lds0);
    async_ld16(vt_ + voff1, (char*)Vs[b] + lds1);
  };

  auto compute = [&](int kt, int b, bool domask) {
    f32x16 S = {};
    __builtin_amdgcn_s_setprio(1);
#pragma unroll
    for (int ksd = 0; ksd < 4; ++ksd) {
      bf16x8 kf = *(const bf16x8*)((char*)Ks[b] + kfo[ksd]);
      S = __builtin_amdgcn_mfma_f32_32x32x16_bf16(kf, qf[ksd], S, 0, 0, 0);
    }
    __builtin_amdgcn_s_setprio(0);

    if (domask) {
#pragma unroll
      for (int r = 0; r < 16; ++r) {
        int ktile = khalf * 32 + (r & 3) + 8 * (r >> 2) + 4 * hi;
        if (kt * 64 + ktile > q0w + l31) S[r] = -1.0e30f;
      }
    }

    float p[16];
#pragma unroll
    for (int r = 0; r < 16; ++r) {
      p[r] = __builtin_amdgcn_exp2f(fminf(S[r] * 1.442695041f, 50.f));
      lsum += p[r];
    }

    uint32_t dw[8];
#pragma unroll
    for (int i = 0; i < 8; ++i) {
      union { bf16_t b2[2]; uint32_t u; } pk;
      pk.b2[0] = (bf16_t)p[2 * i];
      pk.b2[1] = (bf16_t)p[2 * i + 1];
      dw[i] = pk.u;
    }

    bf16x8 pa[2];
#pragma unroll
    for (int kk = 0; kk < 2; ++kk) {
      uint32_t u0 = dw[kk * 4 + 0], u1 = dw[kk * 4 + 1];
      uint32_t u2 = dw[kk * 4 + 2], u3 = dw[kk * 4 + 3];
      uint32_t sa = __shfl_xor(hi ? u0 : u2, 32, 64);
      uint32_t sb = __shfl_xor(hi ? u1 : u3, 32, 64);
      union { uint32_t u[4]; bf16x8 v; } f;
      f.u[0] = hi ? sa : u0;
      f.u[1] = hi ? sb : u1;
      f.u[2] = hi ? u2 : sa;
      f.u[3] = hi ? u3 : sb;
      pa[kk] = f.v;
    }

    __builtin_amdgcn_s_setprio(1);
#pragma unroll
    for (int db = 0; db < 2; ++db)
#pragma unroll
      for (int kk = 0; kk < 2; ++kk) {
        bf16x8 vf = *(const bf16x8*)((char*)Vs[b] + vfo[db][kk]);
        oacc[db] = __builtin_amdgcn_mfma_f32_32x32x16_bf16(pa[kk], vf, oacc[db], 0, 0, 0);
      }
    __builtin_amdgcn_s_setprio(0);
  };

  issue(0, 0);
  int buf = 0;
  for (int kt = 0; kt < nt; ++kt) {
    asm volatile("s_waitcnt vmcnt(0)" ::: "memory");
    __builtin_amdgcn_s_barrier();
    __builtin_amdgcn_sched_barrier(0);
    if (kt + 1 < nt) issue(kt + 1, buf ^ 1);
    compute(kt, buf, kt == nt - 1);
    buf ^= 1;
  }

  lsum += __shfl_xor(lsum, 32, 64);

  __syncthreads();
  float* mO = (float*)Ks;
  float* mL = (float*)Vs;
  if (khalf == 1) {
    float* ob = mO + qsub * 2048;
#pragma unroll
    for (int db = 0; db < 2; ++db)
#pragma unroll
      for (int r = 0; r < 16; ++r)
        ob[(db * 16 + r) * 64 + lane] = oacc[db][r];
    mL[qsub * 32 + l31] = lsum;
  }
  __syncthreads();
  if (khalf == 0) {
    float* ob = mO + qsub * 2048;
    float ltot = lsum + mL[qsub * 32 + l31];
    Linv[qsub * 32 + l31] = 1.f / ltot;
#pragma unroll
    for (int db = 0; db < 2; ++db)
#pragma unroll
      for (int r = 0; r < 16; ++r)
        oacc[db][r] += ob[(db * 16 + r) * 64 + lane];
#pragma unroll
    for (int r = 0; r < 16; ++r) {
      int ro = (r & 3) + 8 * (r >> 2) + 4 * hi;
      int qrow = q0w + ro;
      float inv = Linv[qsub * 32 + ro];
#pragma unroll
      for (int db = 0; db < 2; ++db)
        O[(size_t)(n * T_S + qrow) * D_M + h * D_H + db * 32 + l31] =
            (bf16_t)(oacc[db][r] * inv);
    }
  }
}

extern "C" void kernel_launch(void* const* d_in, const int* in_sizes, int n_in,
                              void* d_out, int out_size, void* d_ws, size_t ws_size,
                              hipStream_t stream) {
  const float* x  = (const float*)d_in[0];
  const float* W  = (const float*)d_in[1];
  const float* pw = (const float*)d_in[2];
  const float* pb = (const float*)d_in[3];
  float* out = (float*)d_out;

  char* ws = (char*)d_ws;
  bf16_t* x_bf = (bf16_t*)(ws);                      //  8 MB: [4096][1024]
  bf16_t* Wt   = (bf16_t*)(ws + (8ull  << 20));      //  6 MB: [3072][1024]
  bf16_t* pwb  = (bf16_t*)(ws + (14ull << 20));      //  2 MB: [1024][1024]
  bf16_t* Qh   = (bf16_t*)(ws + (16ull << 20));      //  8 MB: [2,16,2048,64]
  bf16_t* Kh   = (bf16_t*)(ws + (24ull << 20));      //  8 MB
  bf16_t* Vth  = (bf16_t*)(ws + (32ull << 20));      //  8 MB: [2,16,64,2048]
  bf16_t* Oa   = (bf16_t*)(ws + (40ull << 20));      //  8 MB: [4096][1024]

  // all input prep in one launch: 5120 cvt blocks + 3072 transpose blocks
  prep_kernel<<<8192, 256, 0, stream>>>(x, x_bf, pw, pwb, W, Wt);

  // QKV GEMM: M=4096 (32), N=3072 (32 x 96) -> 1024 blocks = 4/CU, cpx=128
  gemm_bt_kernel<0, 96><<<1024, 256, 0, stream>>>(x_bf, Wt, Qh, Kh, Vth, nullptr, nullptr, 32, 128);

  attn_kernel<<<1024, 256, 0, stream>>>(Qh, Kh, Vth, Oa);

  // proj GEMM: M=4096 (32), N=1024 (16 x 64) -> 512 blocks = 2/CU, cpx=64
  gemm_bt_kernel<1, 64><<<512, 256, 0, stream>>>(Oa, pwb, nullptr, nullptr, nullptr, pb, out, 16, 64);
}

// Round 18
// 108.642 us; speedup vs baseline: 1.1986x; 1.1986x over previous
//
#include <hip/hip_runtime.h>
#include <hip/hip_bf16.h>
#include <stdint.h>

#define N_B 2
#define T_S 2048
#define D_M 1024
#define H_N 16
#define D_H 64

typedef __bf16 bf16_t;
typedef __bf16 bf16x8 __attribute__((ext_vector_type(8)));
typedef float f32x4 __attribute__((ext_vector_type(4)));
typedef float f32x16 __attribute__((ext_vector_type(16)));

__device__ __forceinline__ void async_ld16(const void* g, void* lds_uniform_base) {
  __builtin_amdgcn_global_load_lds(
      (const __attribute__((address_space(1))) uint32_t*)(uintptr_t)g,
      (__attribute__((address_space(3))) uint32_t*)(uintptr_t)lds_uniform_base,
      16, 0, 0);
}

// ---------------- prep: fp32->bf16 cvt (x, proj_w) + W transpose-cvt -------
__global__ __launch_bounds__(256) void prep_kernel(
    const float* __restrict__ x, bf16_t* __restrict__ x_bf,
    const float* __restrict__ pw, bf16_t* __restrict__ pwb,
    const float* __restrict__ W, bf16_t* __restrict__ Wt) {
  __shared__ float tile[32][33];
  const int bid = blockIdx.x;
  if (bid < 5120) {
    int i = bid * 256 + threadIdx.x;
    const float* in = x;
    bf16_t* out = x_bf;
    const int n1 = (4096 * 1024) / 4;
    if (i >= n1) { i -= n1; in = pw; out = pwb; }
    float4 v = ((const float4*)in)[i];
    union { bf16_t b[4]; uint64_t u; } o;
    o.b[0] = (bf16_t)v.x; o.b[1] = (bf16_t)v.y;
    o.b[2] = (bf16_t)v.z; o.b[3] = (bf16_t)v.w;
    *(uint64_t*)(out + (size_t)i * 4) = o.u;
  } else {
    const int tb = bid - 5120;            // 0..3071
    const int bx = (tb % 96) * 32;        // col of W
    const int by = (tb / 96) * 32;        // row of W
    const int tx = threadIdx.x & 31, ty = threadIdx.x >> 5;  // (32,8)
#pragma unroll
    for (int i = 0; i < 32; i += 8)
      tile[ty + i][tx] = W[(size_t)(by + ty + i) * 3072 + bx + tx];
    __syncthreads();
#pragma unroll
    for (int i = 0; i < 32; i += 8)
      Wt[(size_t)(bx + ty + i) * 1024 + by + tx] = (bf16_t)tile[tx][ty + i];
  }
}

// ---------------- bf16 GEMM, C = A @ Bt^T : BM x 128 tile, BK=32 -----------
// r12 pipeline EXACTLY (best measured 44.0us): 2-buffer, counted vmcnt,
// two barriers/step, linear 64B-row LDS (conflicts measured off critical
// path: r13 conflict-free was SLOWER).
// Changes vs r12 are index-math only:
//  - MODE 0 (QKV, BM=128): XCD owns a 2D chunk (8 M-panels x 12 N-panels)
//    -> per-XCD working set A 2MB + B 3MB ~= L2 (was 1+6=7MB, FETCH 46MB).
//  - MODE 1 (proj, BM=64): 512 blocks = 2 blocks/CU (was 256 = 1/CU);
//    per-XCD set 1MB A + 2MB B fits L2.
template <int MODE, int BM>
__global__ __launch_bounds__(256) void gemm_bt_kernel(
    const bf16_t* __restrict__ A, const bf16_t* __restrict__ Bt,
    bf16_t* __restrict__ Qo, bf16_t* __restrict__ Ko, bf16_t* __restrict__ Vto,
    const float* __restrict__ bias, float* __restrict__ Co) {
  constexpr int MI = BM / 32;              // A frags per wave (2 M-waves)
  constexpr int ABYTES = BM * 64;          // A bytes per buffer (64B rows)
  constexpr int NLD = BM / 64 + 2;         // 16B chunks per thread per tile
  __shared__ char lds[2][ABYTES + 8192];

  const int tid = threadIdx.x;
  const int lane = tid & 63;
  const int wid = tid >> 6;
  const int wr = wid >> 1, wc = wid & 1;
  const int g = lane >> 4, lr = lane & 15;
  const int d_ = blockIdx.x;

  int brow, bcol;
  if (MODE == 0) {
    // 768 blocks: xcd -> (rx,cx) 4x2; each owns 8 row-panels x 12 col-panels
    const int xcd = d_ & 7, i_ = d_ >> 3;      // i_ in 0..95
    const int rx = xcd >> 1, cx = xcd & 1;
    brow = ((rx << 3) + i_ / 12) * 128;
    bcol = (cx * 12 + i_ % 12) * 128;
  } else {
    // 512 blocks: xcd-chunked linear, cpx=64; BM=64 rows
    const int orig = (d_ & 7) * 64 + (d_ >> 3);
    brow = (orig >> 3) * 64;
    bcol = (orig & 7) * 128;
  }

  f32x4 acc[MI][4] = {};

  // staging: chunk c: A (c < BM*4): row c>>2, 16B-slot c&3; B: cb = c - BM*4.
  // Linear dest = chunk*16 within section. (r12 layout: 64B rows, no swizzle.)
  const char* gbase[NLD];
  int sdst[NLD];
#pragma unroll
  for (int q = 0; q < NLD; ++q) {
    int c = q * 256 + tid;
    if (c < BM * 4) {
      gbase[q] = (const char*)A + (size_t)(brow + (c >> 2)) * 2048 + (c & 3) * 16;
      sdst[q] = c * 16;
    } else {
      int cb = c - BM * 4;
      gbase[q] = (const char*)Bt + (size_t)(bcol + (cb >> 2)) * 2048 + (cb & 3) * 16;
      sdst[q] = ABYTES + cb * 16;
    }
  }

  auto stage = [&](int t, int b) {
#pragma unroll
    for (int q = 0; q < NLD; ++q)
      async_ld16(gbase[q] + t * 64, lds[b] + sdst[q]);
  };

  stage(0, 0);
  for (int t = 0; t < 32; ++t) {
    if (t + 1 < 32) {
      stage(t + 1, (t + 1) & 1);
      if constexpr (NLD == 4) { asm volatile("s_waitcnt vmcnt(4)" ::: "memory"); }
      else                    { asm volatile("s_waitcnt vmcnt(3)" ::: "memory"); }
    } else {
      asm volatile("s_waitcnt vmcnt(0)" ::: "memory");
    }
    __builtin_amdgcn_s_barrier();
    __builtin_amdgcn_sched_barrier(0);

    const char* base = lds[t & 1];
    bf16x8 af[MI], bfr[4];
#pragma unroll
    for (int i = 0; i < MI; ++i)
      af[i] = *(const bf16x8*)(base + (wr * (BM / 2) + i * 16 + lr) * 64 + g * 16);
#pragma unroll
    for (int j = 0; j < 4; ++j)
      bfr[j] = *(const bf16x8*)(base + ABYTES + (wc * 64 + j * 16 + lr) * 64 + g * 16);
    __builtin_amdgcn_s_setprio(1);
#pragma unroll
    for (int i = 0; i < MI; ++i)
#pragma unroll
      for (int j = 0; j < 4; ++j)
        acc[i][j] = __builtin_amdgcn_mfma_f32_16x16x32_bf16(af[i], bfr[j], acc[i][j], 0, 0, 0);
    __builtin_amdgcn_s_setprio(0);
    asm volatile("s_waitcnt lgkmcnt(0)" ::: "memory");  // reads retired before overwrite
    __builtin_amdgcn_s_barrier();
  }

#pragma unroll
  for (int i = 0; i < MI; ++i) {
    int row0_ = brow + wr * (BM / 2) + i * 16 + g * 4;
#pragma unroll
    for (int j = 0; j < 4; ++j) {
      int col = bcol + wc * 64 + j * 16 + lr;
#pragma unroll
      for (int r = 0; r < 4; ++r) {
        int row = row0_ + r;
        float v = acc[i][j][r];
        if (MODE == 0) {
          int n = row >> 11, t = row & (T_S - 1);
          int which = col >> 10, d = col & (D_M - 1);
          int h = d >> 6, dh = d & 63;
          if (which == 0)
            Qo[((size_t)(n * H_N + h) * T_S + t) * D_H + dh] = (bf16_t)v;
          else if (which == 1)
            Ko[((size_t)(n * H_N + h) * T_S + t) * D_H + dh] = (bf16_t)v;
          else
            Vto[((size_t)(n * H_N + h) * D_H + dh) * T_S + t] = (bf16_t)v;
        } else {
          Co[(size_t)row * D_M + col] = v + bias[col];
        }
      }
    }
  }
}

// ---------------- causal flash attention (swapped-QK, 32x32 MFMA) ----------
// (r9 structure, unchanged)
__global__ __launch_bounds__(256, 4) void attn_kernel(const bf16_t* __restrict__ Q,
                                                      const bf16_t* __restrict__ K,
                                                      const bf16_t* __restrict__ Vt,
                                                      bf16_t* __restrict__ O) {
  __shared__ bf16_t Ks[2][4096];
  __shared__ bf16_t Vs[2][4096];
  __shared__ float Linv[64];

  const int tid = threadIdx.x;
  const int lane = tid & 63;
  const int w = tid >> 6;
  const int qsub = w >> 1, khalf = w & 1;
  const int l31 = lane & 31;
  const int hi = lane >> 5;

  const int d_ = blockIdx.x;       // 0..1023
  const int x = d_ & 7;
  const int s = d_ >> 3;
  const int hs = s & 3, j_ = s >> 2;
  const int t_ = j_ >> 3, m_ = j_ & 7;
  const int qc = (t_ == 0) ? (31 - m_) : (t_ == 1) ? (16 + m_)
               : (t_ == 2) ? (15 - m_) : m_;
  const int nh = x * 4 + hs;
  const bf16_t* Qg = Q + (size_t)nh * T_S * D_H;
  const char* Kb = (const char*)(K + (size_t)nh * T_S * D_H);
  const char* Vb = (const char*)(Vt + (size_t)nh * D_H * T_S);
  const int n = nh >> 4, h = nh & 15;

  const int c0 = (w * 2 + 0) * 64 + lane;
  const int c1 = (w * 2 + 1) * 64 + lane;
  const int r0_ = c0 >> 3, cb0 = (c0 & 7) * 16, sw0 = (r0_ & 7) << 4;
  const int r1_ = c1 >> 3, cb1 = (c1 & 7) * 16, sw1 = (r1_ & 7) << 4;
  const int koff0 = r0_ * 128 + (cb0 ^ sw0), koff1 = r1_ * 128 + (cb1 ^ sw1);
  const int voff0 = r0_ * 4096 + (cb0 ^ sw0), voff1 = r1_ * 4096 + (cb1 ^ sw1);
  const int lds0 = (w * 2 + 0) * 1024, lds1 = (w * 2 + 1) * 1024;

  const int q0w = qc * 64 + qsub * 32;
  const int nt = qc + 1;

  bf16x8 qf[4];
#pragma unroll
  for (int ksd = 0; ksd < 4; ++ksd) {
    bf16x8 t = *(const bf16x8*)(Qg + (size_t)(q0w + l31) * D_H + ksd * 16 + hi * 8);
#pragma unroll
    for (int e = 0; e < 8; ++e) t[e] = (bf16_t)((float)t[e] * 0.125f);
    qf[ksd] = t;
  }

  const int kabs_ = khalf * 32 + l31;
  int kfo[4];
#pragma unroll
  for (int ksd = 0; ksd < 4; ++ksd)
    kfo[ksd] = (kabs_ * 128 + ksd * 32 + hi * 16) ^ ((kabs_ & 7) << 4);
  int vfo[2][2];
#pragma unroll
  for (int db = 0; db < 2; ++db)
#pragma unroll
    for (int kk = 0; kk < 2; ++kk) {
      int dd = db * 32 + l31;
      vfo[db][kk] = (dd * 128 + khalf * 64 + kk * 32 + hi * 16) ^ ((dd & 7) << 4);
    }

  f32x16 oacc[2] = {};
  float lsum = 0.f;

  auto issue = [&](int t, int b) {
    const char* kt_ = Kb + (size_t)t * 8192;
    const char* vt_ = Vb + (size_t)t * 128;
    async_ld16(kt_ + koff0, (char*)Ks[b] + lds0);
    async_ld16(kt_ + koff1, (char*)Ks[b] + lds1);
    async_ld16(vt_ + voff0, (char*)Vs[b] + lds0);
    async_ld16(vt_ + voff1, (char*)Vs[b] + lds1);
  };

  auto compute = [&](int kt, int b, bool domask) {
    f32x16 S = {};
    __builtin_amdgcn_s_setprio(1);
#pragma unroll
    for (int ksd = 0; ksd < 4; ++ksd) {
      bf16x8 kf = *(const bf16x8*)((char*)Ks[b] + kfo[ksd]);
      S = __builtin_amdgcn_mfma_f32_32x32x16_bf16(kf, qf[ksd], S, 0, 0, 0);
    }
    __builtin_amdgcn_s_setprio(0);

    if (domask) {
#pragma unroll
      for (int r = 0; r < 16; ++r) {
        int ktile = khalf * 32 + (r & 3) + 8 * (r >> 2) + 4 * hi;
        if (kt * 64 + ktile > q0w + l31) S[r] = -1.0e30f;
      }
    }

    float p[16];
#pragma unroll
    for (int r = 0; r < 16; ++r) {
      p[r] = __builtin_amdgcn_exp2f(fminf(S[r] * 1.442695041f, 50.f));
      lsum += p[r];
    }

    uint32_t dw[8];
#pragma unroll
    for (int i = 0; i < 8; ++i) {
      union { bf16_t b2[2]; uint32_t u; } pk;
      pk.b2[0] = (bf16_t)p[2 * i];
      pk.b2[1] = (bf16_t)p[2 * i + 1];
      dw[i] = pk.u;
    }

    bf16x8 pa[2];
#pragma unroll
    for (int kk = 0; kk < 2; ++kk) {
      uint32_t u0 = dw[kk * 4 + 0], u1 = dw[kk * 4 + 1];
      uint32_t u2 = dw[kk * 4 + 2], u3 = dw[kk * 4 + 3];
      uint32_t sa = __shfl_xor(hi ? u0 : u2, 32, 64);
      uint32_t sb = __shfl_xor(hi ? u1 : u3, 32, 64);
      union { uint32_t u[4]; bf16x8 v; } f;
      f.u[0] = hi ? sa : u0;
      f.u[1] = hi ? sb : u1;
      f.u[2] = hi ? u2 : sa;
      f.u[3] = hi ? u3 : sb;
      pa[kk] = f.v;
    }

    __builtin_amdgcn_s_setprio(1);
#pragma unroll
    for (int db = 0; db < 2; ++db)
#pragma unroll
      for (int kk = 0; kk < 2; ++kk) {
        bf16x8 vf = *(const bf16x8*)((char*)Vs[b] + vfo[db][kk]);
        oacc[db] = __builtin_amdgcn_mfma_f32_32x32x16_bf16(pa[kk], vf, oacc[db], 0, 0, 0);
      }
    __builtin_amdgcn_s_setprio(0);
  };

  issue(0, 0);
  int buf = 0;
  for (int kt = 0; kt < nt; ++kt) {
    asm volatile("s_waitcnt vmcnt(0)" ::: "memory");
    __builtin_amdgcn_s_barrier();
    __builtin_amdgcn_sched_barrier(0);
    if (kt + 1 < nt) issue(kt + 1, buf ^ 1);
    compute(kt, buf, kt == nt - 1);
    buf ^= 1;
  }

  lsum += __shfl_xor(lsum, 32, 64);

  __syncthreads();
  float* mO = (float*)Ks;
  float* mL = (float*)Vs;
  if (khalf == 1) {
    float* ob = mO + qsub * 2048;
#pragma unroll
    for (int db = 0; db < 2; ++db)
#pragma unroll
      for (int r = 0; r < 16; ++r)
        ob[(db * 16 + r) * 64 + lane] = oacc[db][r];
    mL[qsub * 32 + l31] = lsum;
  }
  __syncthreads();
  if (khalf == 0) {
    float* ob = mO + qsub * 2048;
    float ltot = lsum + mL[qsub * 32 + l31];
    Linv[qsub * 32 + l31] = 1.f / ltot;
#pragma unroll
    for (int db = 0; db < 2; ++db)
#pragma unroll
      for (int r = 0; r < 16; ++r)
        oacc[db][r] += ob[(db * 16 + r) * 64 + lane];
#pragma unroll
    for (int r = 0; r < 16; ++r) {
      int ro = (r & 3) + 8 * (r >> 2) + 4 * hi;
      int qrow = q0w + ro;
      float inv = Linv[qsub * 32 + ro];
#pragma unroll
      for (int db = 0; db < 2; ++db)
        O[(size_t)(n * T_S + qrow) * D_M + h * D_H + db * 32 + l31] =
            (bf16_t)(oacc[db][r] * inv);
    }
  }
}

extern "C" void kernel_launch(void* const* d_in, const int* in_sizes, int n_in,
                              void* d_out, int out_size, void* d_ws, size_t ws_size,
                              hipStream_t stream) {
  const float* x  = (const float*)d_in[0];
  const float* W  = (const float*)d_in[1];
  const float* pw = (const float*)d_in[2];
  const float* pb = (const float*)d_in[3];
  float* out = (float*)d_out;

  char* ws = (char*)d_ws;
  bf16_t* x_bf = (bf16_t*)(ws);                      //  8 MB: [4096][1024]
  bf16_t* Wt   = (bf16_t*)(ws + (8ull  << 20));      //  6 MB: [3072][1024]
  bf16_t* pwb  = (bf16_t*)(ws + (14ull << 20));      //  2 MB: [1024][1024]
  bf16_t* Qh   = (bf16_t*)(ws + (16ull << 20));      //  8 MB: [2,16,2048,64]
  bf16_t* Kh   = (bf16_t*)(ws + (24ull << 20));      //  8 MB
  bf16_t* Vth  = (bf16_t*)(ws + (32ull << 20));      //  8 MB: [2,16,64,2048]
  bf16_t* Oa   = (bf16_t*)(ws + (40ull << 20));      //  8 MB: [4096][1024]

  // all input prep in one launch: 5120 cvt blocks + 3072 transpose blocks
  prep_kernel<<<8192, 256, 0, stream>>>(x, x_bf, pw, pwb, W, Wt);

  // QKV GEMM: 128x128 tiles, 768 blocks (3/CU), XCD 2D-chunk mapping
  gemm_bt_kernel<0, 128><<<768, 256, 0, stream>>>(x_bf, Wt, Qh, Kh, Vth, nullptr, nullptr);

  attn_kernel<<<1024, 256, 0, stream>>>(Qh, Kh, Vth, Oa);

  // proj GEMM: 64x128 tiles, 512 blocks (2/CU), xcd-chunked cpx=64
  gemm_bt_kernel<1, 64><<<512, 256, 0, stream>>>(Oa, pwb, nullptr, nullptr, nullptr, pb, out);
}

// Round 19
// 100.416 us; speedup vs baseline: 1.2968x; 1.0819x over previous
//
#include <hip/hip_runtime.h>
#include <hip/hip_bf16.h>
#include <stdint.h>

#define N_B 2
#define T_S 2048
#define D_M 1024
#define H_N 16
#define D_H 64

typedef __bf16 bf16_t;
typedef __bf16 bf16x8 __attribute__((ext_vector_type(8)));
typedef float f32x4 __attribute__((ext_vector_type(4)));
typedef float f32x16 __attribute__((ext_vector_type(16)));

__device__ __forceinline__ void async_ld16(const void* g, void* lds_uniform_base) {
  __builtin_amdgcn_global_load_lds(
      (const __attribute__((address_space(1))) uint32_t*)(uintptr_t)g,
      (__attribute__((address_space(3))) uint32_t*)(uintptr_t)lds_uniform_base,
      16, 0, 0);
}

// ---------------- prep: fp32->bf16 cvt (x, proj_w) + W transpose-cvt -------
__global__ __launch_bounds__(256) void prep_kernel(
    const float* __restrict__ x, bf16_t* __restrict__ x_bf,
    const float* __restrict__ pw, bf16_t* __restrict__ pwb,
    const float* __restrict__ W, bf16_t* __restrict__ Wt) {
  __shared__ float tile[32][33];
  const int bid = blockIdx.x;
  if (bid < 5120) {
    int i = bid * 256 + threadIdx.x;
    const float* in = x;
    bf16_t* out = x_bf;
    const int n1 = (4096 * 1024) / 4;
    if (i >= n1) { i -= n1; in = pw; out = pwb; }
    float4 v = ((const float4*)in)[i];
    union { bf16_t b[4]; uint64_t u; } o;
    o.b[0] = (bf16_t)v.x; o.b[1] = (bf16_t)v.y;
    o.b[2] = (bf16_t)v.z; o.b[3] = (bf16_t)v.w;
    *(uint64_t*)(out + (size_t)i * 4) = o.u;
  } else {
    const int tb = bid - 5120;            // 0..3071
    const int bx = (tb % 96) * 32;        // col of W
    const int by = (tb / 96) * 32;        // row of W
    const int tx = threadIdx.x & 31, ty = threadIdx.x >> 5;  // (32,8)
#pragma unroll
    for (int i = 0; i < 32; i += 8)
      tile[ty + i][tx] = W[(size_t)(by + ty + i) * 3072 + bx + tx];
    __syncthreads();
#pragma unroll
    for (int i = 0; i < 32; i += 8)
      Wt[(size_t)(bx + ty + i) * 1024 + by + tx] = (bf16_t)tile[tx][ty + i];
  }
}

// ---------------- QKV GEMM: exact r12 config (measured best: 44.0us) -------
// 128^2 tile, BK=32, 2-buffer, counted vmcnt(4), two barriers/step, linear
// 64B-row LDS (conflicts measured off critical path), xcd-chunked cpx=96.
__global__ __launch_bounds__(256) void gemm_qkv_kernel(
    const bf16_t* __restrict__ A, const bf16_t* __restrict__ Bt,
    bf16_t* __restrict__ Qo, bf16_t* __restrict__ Ko, bf16_t* __restrict__ Vto) {
  __shared__ bf16_t As[2][4096];
  __shared__ bf16_t Bs[2][4096];
  const int tid = threadIdx.x;
  const int lane = tid & 63;
  const int wid = tid >> 6;
  const int wr = wid >> 1, wc = wid & 1;
  const int g = lane >> 4, lr = lane & 15;
  const int d_ = blockIdx.x;
  const int orig = (d_ & 7) * 96 + (d_ >> 3);
  const int brow = (orig / 24) * 128;
  const int bcol = (orig % 24) * 128;

  f32x4 acc[4][4] = {};

  // per-thread staging: 2 A-chunks + 2 B-chunks of 16B per K-tile (r12 exact)
  const int idx0 = wid * 128 + lane;
  const int idx1 = wid * 128 + 64 + lane;
  const int row0 = idx0 >> 2, part0 = (idx0 & 3) * 8;
  const int row1 = idx1 >> 2, part1 = (idx1 & 3) * 8;
  const int dst0 = (wid * 128) * 8;
  const int dst1 = (wid * 128 + 64) * 8;

  auto stage = [&](int t, int b) {
    async_ld16(A + (size_t)(brow + row0) * 1024 + t * 32 + part0, &As[b][dst0]);
    async_ld16(Bt + (size_t)(bcol + row0) * 1024 + t * 32 + part0, &Bs[b][dst0]);
    async_ld16(A + (size_t)(brow + row1) * 1024 + t * 32 + part1, &As[b][dst1]);
    async_ld16(Bt + (size_t)(bcol + row1) * 1024 + t * 32 + part1, &Bs[b][dst1]);
  };

  stage(0, 0);
  for (int t = 0; t < 32; ++t) {
    if (t + 1 < 32) {
      stage(t + 1, (t + 1) & 1);
      asm volatile("s_waitcnt vmcnt(4)" ::: "memory");  // tile t landed; t+1 in flight
    } else {
      asm volatile("s_waitcnt vmcnt(0)" ::: "memory");
    }
    __builtin_amdgcn_s_barrier();
    __builtin_amdgcn_sched_barrier(0);

    const bf16_t* as = As[t & 1];
    const bf16_t* bs = Bs[t & 1];
    bf16x8 af[4], bfr[4];
#pragma unroll
    for (int i = 0; i < 4; ++i) {
      af[i]  = *(const bf16x8*)&as[(wr * 64 + i * 16 + lr) * 32 + g * 8];
      bfr[i] = *(const bf16x8*)&bs[(wc * 64 + i * 16 + lr) * 32 + g * 8];
    }
    __builtin_amdgcn_s_setprio(1);
#pragma unroll
    for (int i = 0; i < 4; ++i)
#pragma unroll
      for (int j = 0; j < 4; ++j)
        acc[i][j] = __builtin_amdgcn_mfma_f32_16x16x32_bf16(af[i], bfr[j], acc[i][j], 0, 0, 0);
    __builtin_amdgcn_s_setprio(0);
    asm volatile("s_waitcnt lgkmcnt(0)" ::: "memory");  // reads retired before overwrite
    __builtin_amdgcn_s_barrier();
  }

#pragma unroll
  for (int i = 0; i < 4; ++i) {
    int row0_ = brow + wr * 64 + i * 16 + g * 4;
#pragma unroll
    for (int j = 0; j < 4; ++j) {
      int col = bcol + wc * 64 + j * 16 + lr;
      int which = col >> 10, d = col & (D_M - 1);
      int h = d >> 6, dh = d & 63;
#pragma unroll
      for (int r = 0; r < 4; ++r) {
        int row = row0_ + r;
        int n = row >> 11, t = row & (T_S - 1);
        float v = acc[i][j][r];
        if (which == 0)
          Qo[((size_t)(n * H_N + h) * T_S + t) * D_H + dh] = (bf16_t)v;
        else if (which == 1)
          Ko[((size_t)(n * H_N + h) * T_S + t) * D_H + dh] = (bf16_t)v;
        else
          Vto[((size_t)(n * H_N + h) * D_H + dh) * T_S + t] = (bf16_t)v;
      }
    }
  }
}

// ---------------- proj GEMM: r18's BM=64 variant (measured ~9.5us) ---------
// 64x128 tile, 512 blocks = 2/CU, same r12 pipeline, vmcnt(3).
__global__ __launch_bounds__(256) void gemm_proj_kernel(
    const bf16_t* __restrict__ A, const bf16_t* __restrict__ Bt,
    const float* __restrict__ bias, float* __restrict__ Co) {
  constexpr int BM = 64;
  constexpr int ABYTES = BM * 64;          // 4096
  __shared__ char lds[2][ABYTES + 8192];

  const int tid = threadIdx.x;
  const int lane = tid & 63;
  const int wid = tid >> 6;
  const int wr = wid >> 1, wc = wid & 1;
  const int g = lane >> 4, lr = lane & 15;
  const int d_ = blockIdx.x;
  const int orig = (d_ & 7) * 64 + (d_ >> 3);
  const int brow = (orig >> 3) * 64;
  const int bcol = (orig & 7) * 128;

  f32x4 acc[2][4] = {};

  const char* gbase[3];
  int sdst[3];
#pragma unroll
  for (int q = 0; q < 3; ++q) {
    int c = q * 256 + tid;
    if (c < BM * 4) {
      gbase[q] = (const char*)A + (size_t)(brow + (c >> 2)) * 2048 + (c & 3) * 16;
      sdst[q] = c * 16;
    } else {
      int cb = c - BM * 4;
      gbase[q] = (const char*)Bt + (size_t)(bcol + (cb >> 2)) * 2048 + (cb & 3) * 16;
      sdst[q] = ABYTES + cb * 16;
    }
  }

  auto stage = [&](int t, int b) {
#pragma unroll
    for (int q = 0; q < 3; ++q)
      async_ld16(gbase[q] + t * 64, lds[b] + sdst[q]);
  };

  stage(0, 0);
  for (int t = 0; t < 32; ++t) {
    if (t + 1 < 32) {
      stage(t + 1, (t + 1) & 1);
      asm volatile("s_waitcnt vmcnt(3)" ::: "memory");
    } else {
      asm volatile("s_waitcnt vmcnt(0)" ::: "memory");
    }
    __builtin_amdgcn_s_barrier();
    __builtin_amdgcn_sched_barrier(0);

    const char* base = lds[t & 1];
    bf16x8 af[2], bfr[4];
#pragma unroll
    for (int i = 0; i < 2; ++i)
      af[i] = *(const bf16x8*)(base + (wr * 32 + i * 16 + lr) * 64 + g * 16);
#pragma unroll
    for (int j = 0; j < 4; ++j)
      bfr[j] = *(const bf16x8*)(base + ABYTES + (wc * 64 + j * 16 + lr) * 64 + g * 16);
    __builtin_amdgcn_s_setprio(1);
#pragma unroll
    for (int i = 0; i < 2; ++i)
#pragma unroll
      for (int j = 0; j < 4; ++j)
        acc[i][j] = __builtin_amdgcn_mfma_f32_16x16x32_bf16(af[i], bfr[j], acc[i][j], 0, 0, 0);
    __builtin_amdgcn_s_setprio(0);
    asm volatile("s_waitcnt lgkmcnt(0)" ::: "memory");
    __builtin_amdgcn_s_barrier();
  }

#pragma unroll
  for (int i = 0; i < 2; ++i) {
    int row0_ = brow + wr * 32 + i * 16 + g * 4;
#pragma unroll
    for (int j = 0; j < 4; ++j) {
      int col = bcol + wc * 64 + j * 16 + lr;
      float b = bias[col];
#pragma unroll
      for (int r = 0; r < 4; ++r)
        Co[(size_t)(row0_ + r) * D_M + col] = acc[i][j][r] + b;
    }
  }
}

// ---------------- causal flash attention (swapped-QK, 32x32 MFMA) ----------
// (r9 structure, unchanged)
__global__ __launch_bounds__(256, 4) void attn_kernel(const bf16_t* __restrict__ Q,
                                                      const bf16_t* __restrict__ K,
                                                      const bf16_t* __restrict__ Vt,
                                                      bf16_t* __restrict__ O) {
  __shared__ bf16_t Ks[2][4096];
  __shared__ bf16_t Vs[2][4096];
  __shared__ float Linv[64];

  const int tid = threadIdx.x;
  const int lane = tid & 63;
  const int w = tid >> 6;
  const int qsub = w >> 1, khalf = w & 1;
  const int l31 = lane & 31;
  const int hi = lane >> 5;

  const int d_ = blockIdx.x;       // 0..1023
  const int x = d_ & 7;
  const int s = d_ >> 3;
  const int hs = s & 3, j_ = s >> 2;
  const int t_ = j_ >> 3, m_ = j_ & 7;
  const int qc = (t_ == 0) ? (31 - m_) : (t_ == 1) ? (16 + m_)
               : (t_ == 2) ? (15 - m_) : m_;
  const int nh = x * 4 + hs;
  const bf16_t* Qg = Q + (size_t)nh * T_S * D_H;
  const char* Kb = (const char*)(K + (size_t)nh * T_S * D_H);
  const char* Vb = (const char*)(Vt + (size_t)nh * D_H * T_S);
  const int n = nh >> 4, h = nh & 15;

  const int c0 = (w * 2 + 0) * 64 + lane;
  const int c1 = (w * 2 + 1) * 64 + lane;
  const int r0_ = c0 >> 3, cb0 = (c0 & 7) * 16, sw0 = (r0_ & 7) << 4;
  const int r1_ = c1 >> 3, cb1 = (c1 & 7) * 16, sw1 = (r1_ & 7) << 4;
  const int koff0 = r0_ * 128 + (cb0 ^ sw0), koff1 = r1_ * 128 + (cb1 ^ sw1);
  const int voff0 = r0_ * 4096 + (cb0 ^ sw0), voff1 = r1_ * 4096 + (cb1 ^ sw1);
  const int lds0 = (w * 2 + 0) * 1024, lds1 = (w * 2 + 1) * 1024;

  const int q0w = qc * 64 + qsub * 32;
  const int nt = qc + 1;

  bf16x8 qf[4];
#pragma unroll
  for (int ksd = 0; ksd < 4; ++ksd) {
    bf16x8 t = *(const bf16x8*)(Qg + (size_t)(q0w + l31) * D_H + ksd * 16 + hi * 8);
#pragma unroll
    for (int e = 0; e < 8; ++e) t[e] = (bf16_t)((float)t[e] * 0.125f);
    qf[ksd] = t;
  }

  const int kabs_ = khalf * 32 + l31;
  int kfo[4];
#pragma unroll
  for (int ksd = 0; ksd < 4; ++ksd)
    kfo[ksd] = (kabs_ * 128 + ksd * 32 + hi * 16) ^ ((kabs_ & 7) << 4);
  int vfo[2][2];
#pragma unroll
  for (int db = 0; db < 2; ++db)
#pragma unroll
    for (int kk = 0; kk < 2; ++kk) {
      int dd = db * 32 + l31;
      vfo[db][kk] = (dd * 128 + khalf * 64 + kk * 32 + hi * 16) ^ ((dd & 7) << 4);
    }

  f32x16 oacc[2] = {};
  float lsum = 0.f;

  auto issue = [&](int t, int b) {
    const char* kt_ = Kb + (size_t)t * 8192;
    const char* vt_ = Vb + (size_t)t * 128;
    async_ld16(kt_ + koff0, (char*)Ks[b] + lds0);
    async_ld16(kt_ + koff1, (char*)Ks[b] + lds1);
    async_ld16(vt_ + voff0, (char*)Vs[b] + lds0);
    async_ld16(vt_ + voff1, (char*)Vs[b] + lds1);
  };

  auto compute = [&](int kt, int b, bool domask) {
    f32x16 S = {};
    __builtin_amdgcn_s_setprio(1);
#pragma unroll
    for (int ksd = 0; ksd < 4; ++ksd) {
      bf16x8 kf = *(const bf16x8*)((char*)Ks[b] + kfo[ksd]);
      S = __builtin_amdgcn_mfma_f32_32x32x16_bf16(kf, qf[ksd], S, 0, 0, 0);
    }
    __builtin_amdgcn_s_setprio(0);

    if (domask) {
#pragma unroll
      for (int r = 0; r < 16; ++r) {
        int ktile = khalf * 32 + (r & 3) + 8 * (r >> 2) + 4 * hi;
        if (kt * 64 + ktile > q0w + l31) S[r] = -1.0e30f;
      }
    }

    float p[16];
#pragma unroll
    for (int r = 0; r < 16; ++r) {
      p[r] = __builtin_amdgcn_exp2f(fminf(S[r] * 1.442695041f, 50.f));
      lsum += p[r];
    }

    uint32_t dw[8];
#pragma unroll
    for (int i = 0; i < 8; ++i) {
      union { bf16_t b2[2]; uint32_t u; } pk;
      pk.b2[0] = (bf16_t)p[2 * i];
      pk.b2[1] = (bf16_t)p[2 * i + 1];
      dw[i] = pk.u;
    }

    bf16x8 pa[2];
#pragma unroll
    for (int kk = 0; kk < 2; ++kk) {
      uint32_t u0 = dw[kk * 4 + 0], u1 = dw[kk * 4 + 1];
      uint32_t u2 = dw[kk * 4 + 2], u3 = dw[kk * 4 + 3];
      uint32_t sa = __shfl_xor(hi ? u0 : u2, 32, 64);
      uint32_t sb = __shfl_xor(hi ? u1 : u3, 32, 64);
      union { uint32_t u[4]; bf16x8 v; } f;
      f.u[0] = hi ? sa : u0;
      f.u[1] = hi ? sb : u1;
      f.u[2] = hi ? u2 : sa;
      f.u[3] = hi ? u3 : sb;
      pa[kk] = f.v;
    }

    __builtin_amdgcn_s_setprio(1);
#pragma unroll
    for (int db = 0; db < 2; ++db)
#pragma unroll
      for (int kk = 0; kk < 2; ++kk) {
        bf16x8 vf = *(const bf16x8*)((char*)Vs[b] + vfo[db][kk]);
        oacc[db] = __builtin_amdgcn_mfma_f32_32x32x16_bf16(pa[kk], vf, oacc[db], 0, 0, 0);
      }
    __builtin_amdgcn_s_setprio(0);
  };

  issue(0, 0);
  int buf = 0;
  for (int kt = 0; kt < nt; ++kt) {
    asm volatile("s_waitcnt vmcnt(0)" ::: "memory");
    __builtin_amdgcn_s_barrier();
    __builtin_amdgcn_sched_barrier(0);
    if (kt + 1 < nt) issue(kt + 1, buf ^ 1);
    compute(kt, buf, kt == nt - 1);
    buf ^= 1;
  }

  lsum += __shfl_xor(lsum, 32, 64);

  __syncthreads();
  float* mO = (float*)Ks;
  float* mL = (float*)Vs;
  if (khalf == 1) {
    float* ob = mO + qsub * 2048;
#pragma unroll
    for (int db = 0; db < 2; ++db)
#pragma unroll
      for (int r = 0; r < 16; ++r)
        ob[(db * 16 + r) * 64 + lane] = oacc[db][r];
    mL[qsub * 32 + l31] = lsum;
  }
  __syncthreads();
  if (khalf == 0) {
    float* ob = mO + qsub * 2048;
    float ltot = lsum + mL[qsub * 32 + l31];
    Linv[qsub * 32 + l31] = 1.f / ltot;
#pragma unroll
    for (int db = 0; db < 2; ++db)
#pragma unroll
      for (int r = 0; r < 16; ++r)
        oacc[db][r] += ob[(db * 16 + r) * 64 + lane];
#pragma unroll
    for (int r = 0; r < 16; ++r) {
      int ro = (r & 3) + 8 * (r >> 2) + 4 * hi;
      int qrow = q0w + ro;
      float inv = Linv[qsub * 32 + ro];
#pragma unroll
      for (int db = 0; db < 2; ++db)
        O[(size_t)(n * T_S + qrow) * D_M + h * D_H + db * 32 + l31] =
            (bf16_t)(oacc[db][r] * inv);
    }
  }
}

extern "C" void kernel_launch(void* const* d_in, const int* in_sizes, int n_in,
                              void* d_out, int out_size, void* d_ws, size_t ws_size,
                              hipStream_t stream) {
  const float* x  = (const float*)d_in[0];
  const float* W  = (const float*)d_in[1];
  const float* pw = (const float*)d_in[2];
  const float* pb = (const float*)d_in[3];
  float* out = (float*)d_out;

  char* ws = (char*)d_ws;
  bf16_t* x_bf = (bf16_t*)(ws);                      //  8 MB: [4096][1024]
  bf16_t* Wt   = (bf16_t*)(ws + (8ull  << 20));      //  6 MB: [3072][1024]
  bf16_t* pwb  = (bf16_t*)(ws + (14ull << 20));      //  2 MB: [1024][1024]
  bf16_t* Qh   = (bf16_t*)(ws + (16ull << 20));      //  8 MB: [2,16,2048,64]
  bf16_t* Kh   = (bf16_t*)(ws + (24ull << 20));      //  8 MB
  bf16_t* Vth  = (bf16_t*)(ws + (32ull << 20));      //  8 MB: [2,16,64,2048]
  bf16_t* Oa   = (bf16_t*)(ws + (40ull << 20));      //  8 MB: [4096][1024]

  // all input prep in one launch: 5120 cvt blocks + 3072 transpose blocks
  prep_kernel<<<8192, 256, 0, stream>>>(x, x_bf, pw, pwb, W, Wt);

  // QKV GEMM: exact r12 config, 768 blocks (3/CU), cpx=96
  gemm_qkv_kernel<<<768, 256, 0, stream>>>(x_bf, Wt, Qh, Kh, Vth);

  attn_kernel<<<1024, 256, 0, stream>>>(Qh, Kh, Vth, Oa);

  // proj GEMM: 64x128 tiles, 512 blocks (2/CU)
  gemm_proj_kernel<<<512, 256, 0, stream>>>(Oa, pwb, pb, out);
}